// Round 1
// baseline (1203.757 us; speedup 1.0000x reference)
//
#include <hip/hip_runtime.h>
#include <cfloat>

#define NPTS 8192
#define KNN 16

// ---------------------------------------------------------------------------
// Kernel 1: x = feat @ fc1.T + b ; q,k,v = x @ {wq,wk,wv}.T   (8 points/block)
// ---------------------------------------------------------------------------
__global__ __launch_bounds__(128, 2)
void proj_kernel(const float* __restrict__ feat,
                 const float* __restrict__ fc1_w, const float* __restrict__ fc1_b,
                 const float* __restrict__ wq, const float* __restrict__ wk,
                 const float* __restrict__ wv,
                 float* __restrict__ q_ws, float* __restrict__ k_ws,
                 float* __restrict__ v_ws)
{
    __shared__ float fl[8][3];
    __shared__ float xl[8][128];
    const int c = threadIdx.x;
    const long base = (long)blockIdx.x * 8;

    if (c < 24) {
        int p = c / 3, d = c % 3;
        long pt = base + p;
        int b = (int)(pt >> 13), n = (int)(pt & 8191);
        fl[p][d] = feat[((long)b * 3 + d) * NPTS + n];
    }
    __syncthreads();

    float w0 = fc1_w[c*3+0], w1 = fc1_w[c*3+1], w2 = fc1_w[c*3+2], b0 = fc1_b[c];
    #pragma unroll
    for (int p = 0; p < 8; ++p)
        xl[p][c] = fmaf(w0, fl[p][0], fmaf(w1, fl[p][1], fmaf(w2, fl[p][2], b0)));
    __syncthreads();

    float aq[8], ak[8], av[8];
    #pragma unroll
    for (int p = 0; p < 8; ++p) { aq[p] = 0.f; ak[p] = 0.f; av[p] = 0.f; }

    const float4* wq4 = (const float4*)(wq + c*128);
    const float4* wk4 = (const float4*)(wk + c*128);
    const float4* wv4 = (const float4*)(wv + c*128);
    for (int i4 = 0; i4 < 32; ++i4) {
        float4 a = wq4[i4], bw = wk4[i4], cw = wv4[i4];
        #pragma unroll
        for (int p = 0; p < 8; ++p) {
            float4 x = *(const float4*)&xl[p][i4*4];
            aq[p] = fmaf(a.x,x.x, fmaf(a.y,x.y, fmaf(a.z,x.z, fmaf(a.w,x.w, aq[p]))));
            ak[p] = fmaf(bw.x,x.x,fmaf(bw.y,x.y,fmaf(bw.z,x.z,fmaf(bw.w,x.w, ak[p]))));
            av[p] = fmaf(cw.x,x.x,fmaf(cw.y,x.y,fmaf(cw.z,x.z,fmaf(cw.w,x.w, av[p]))));
        }
    }
    #pragma unroll
    for (int p = 0; p < 8; ++p) {
        long pt = base + p;
        q_ws[pt*128 + c] = aq[p];
        k_ws[pt*128 + c] = ak[p];
        v_ws[pt*128 + c] = av[p];
    }
}

// ---------------------------------------------------------------------------
// Kernel 2: brute-force KNN (16 nearest incl. self). 16 queries/block,
// 8 threads/query. Register sorted top-16 + LDS ring, wave-synced drains.
// ---------------------------------------------------------------------------
#define QPB 16
#define TPQ 8
#define CPT 1024

__global__ __launch_bounds__(128, 2)
void knn_kernel(const float* __restrict__ xyz, int* __restrict__ knn)
{
    __shared__ float ringd[128][17];
    __shared__ int   ringi[128][17];
    __shared__ float cdl[QPB][TPQ*KNN + 1];
    __shared__ int   cil[QPB][TPQ*KNN + 1];

    const int t  = threadIdx.x;
    const int ql = t >> 3, s = t & 7;
    const long qpt = (long)blockIdx.x * QPB + ql;
    const int b = (int)(qpt >> 13), n = (int)(qpt & 8191);
    const float* xg = xyz + (long)b * 3 * NPTS;
    const float qx = xg[n], qy = xg[NPTS + n], qz = xg[2*NPTS + n];

    float ad[16];
    int   ai[16];
    #pragma unroll
    for (int i = 0; i < 16; ++i) { ad[i] = FLT_MAX; ai[i] = -1; }
    int wcnt = 0;

    auto insert16 = [&](float d, int idx) {
        bool hi = true;
        #pragma unroll
        for (int sl = 15; sl >= 1; --sl) {
            bool sw = d < ad[sl-1];
            float nd = sw ? ad[sl-1] : (hi ? d   : ad[sl]);
            int   ni = sw ? ai[sl-1] : (hi ? idx : ai[sl]);
            ad[sl] = nd; ai[sl] = ni;
            hi = hi && sw;
        }
        ad[0] = hi ? d   : ad[0];
        ai[0] = hi ? idx : ai[0];
    };
    auto drain = [&]() {
        for (int w = 0; w < wcnt; ++w) {
            float d = ringd[t][w]; int idx = ringi[t][w];
            if (d < ad[15]) insert16(d, idx);
        }
        wcnt = 0;
    };

    const int base = s * CPT;
    for (int it = 0; it < CPT; ++it) {
        int m = base + it;
        float dx = qx - xg[m], dy = qy - xg[NPTS+m], dz = qz - xg[2*NPTS+m];
        float d = fmaf(dx, dx, fmaf(dy, dy, dz*dz));
        if (d < ad[15]) { ringd[t][wcnt] = d; ringi[t][wcnt] = m; ++wcnt; }
        if (__any(wcnt >= 12)) drain();
    }
    drain();

    #pragma unroll
    for (int i = 0; i < 16; ++i) { cdl[ql][s*16+i] = ad[i]; cil[ql][s*16+i] = ai[i]; }
    __syncthreads();

    #pragma unroll
    for (int i = 0; i < 16; ++i) {
        float dk = ad[i]; int ik = ai[i];
        int rank = 0;
        for (int j = 0; j < TPQ*KNN; ++j) {
            float dj = cdl[ql][j];
            rank += (dj < dk) || (dj == dk && cil[ql][j] < ik) ? 1 : 0;
        }
        if (rank < KNN) knn[qpt*KNN + rank] = ik;
    }
}

// ---------------------------------------------------------------------------
// Kernel 3: fused point-transformer attention. 2 points/block, 128 threads
// (thread = channel). All (K,128) intermediates in LDS, acc[2][16] reg tile.
// ---------------------------------------------------------------------------
__global__ __launch_bounds__(128, 2)
void attn_kernel(const float* __restrict__ xyz, const float* __restrict__ feat,
                 const float* __restrict__ d1_w, const float* __restrict__ d1_b,
                 const float* __restrict__ d2_w, const float* __restrict__ d2_b,
                 const float* __restrict__ g1_w, const float* __restrict__ g1_b,
                 const float* __restrict__ g2_w, const float* __restrict__ g2_b,
                 const float* __restrict__ fc2_w, const float* __restrict__ fc2_b,
                 const float* __restrict__ q_ws, const float* __restrict__ k_ws,
                 const float* __restrict__ v_ws, const int* __restrict__ knn,
                 float* __restrict__ out)
{
    __shared__ float bufA[2][16][128];   // h1 -> h -> gh -> logits
    __shared__ float bufP[2][16][128];   // pos
    __shared__ float rel[2][16][4];
    __shared__ float resl[2][128];
    __shared__ int   idxs[2][16];

    const int c = threadIdx.x;
    const long pbase = (long)blockIdx.x * 2;
    const int b = (int)(pbase >> 13);
    const long bofs = (long)b * NPTS;

    if (c < 32) {
        int p = c >> 4, j = c & 15;
        long pt = pbase + p;
        int n = (int)(pt & 8191);
        int m = knn[pt*16 + j];
        idxs[p][j] = m;
        const float* xg = xyz + (long)b*3*NPTS;
        rel[p][j][0] = xg[n]        - xg[m];
        rel[p][j][1] = xg[NPTS+n]   - xg[NPTS+m];
        rel[p][j][2] = xg[2*NPTS+n] - xg[2*NPTS+m];
    }
    __syncthreads();

    // stage 1: h1 = relu(rel @ d1.T + b)
    {
        float w0 = d1_w[c*3], w1 = d1_w[c*3+1], w2 = d1_w[c*3+2], b0 = d1_b[c];
        #pragma unroll
        for (int p = 0; p < 2; ++p)
            #pragma unroll
            for (int j = 0; j < 16; ++j) {
                float v = fmaf(w0, rel[p][j][0],
                          fmaf(w1, rel[p][j][1],
                          fmaf(w2, rel[p][j][2], b0)));
                bufA[p][j][c] = fmaxf(v, 0.f);
            }
    }
    __syncthreads();

    float acc[2][16];
    auto gemv = [&](const float* __restrict__ W) {
        #pragma unroll
        for (int p = 0; p < 2; ++p)
            #pragma unroll
            for (int j = 0; j < 16; ++j) acc[p][j] = 0.f;
        const float4* wrow = (const float4*)(W + c*128);
        for (int i4 = 0; i4 < 32; ++i4) {
            float4 w = wrow[i4];
            #pragma unroll
            for (int p = 0; p < 2; ++p)
                #pragma unroll
                for (int j = 0; j < 16; ++j) {
                    float4 h = *(const float4*)&bufA[p][j][i4*4];
                    acc[p][j] = fmaf(w.x,h.x, fmaf(w.y,h.y,
                                fmaf(w.z,h.z, fmaf(w.w,h.w, acc[p][j]))));
                }
        }
    };

    // stage 2: pos = h1 @ d2.T + b  -> bufP
    gemv(d2_w);
    {
        float b0 = d2_b[c];
        #pragma unroll
        for (int p = 0; p < 2; ++p)
            #pragma unroll
            for (int j = 0; j < 16; ++j) bufP[p][j][c] = acc[p][j] + b0;
    }
    __syncthreads();

    // stage 3: h = q - kg + pos -> bufA
    #pragma unroll
    for (int p = 0; p < 2; ++p) {
        long pt = pbase + p;
        float qv = q_ws[pt*128 + c];
        #pragma unroll
        for (int j = 0; j < 16; ++j) {
            long g = (bofs + idxs[p][j]) * 128 + c;
            bufA[p][j][c] = qv - k_ws[g] + bufP[p][j][c];
        }
    }
    __syncthreads();

    // stage 4: gh = relu(h @ g1.T + b) -> bufA (in place)
    gemv(g1_w);
    __syncthreads();
    {
        float b0 = g1_b[c];
        #pragma unroll
        for (int p = 0; p < 2; ++p)
            #pragma unroll
            for (int j = 0; j < 16; ++j) bufA[p][j][c] = fmaxf(acc[p][j] + b0, 0.f);
    }
    __syncthreads();

    // stage 5: logits = (gh @ g2.T + b) / sqrt(128) -> bufA (in place)
    gemv(g2_w);
    __syncthreads();
    {
        float b0 = g2_b[c];
        const float sc = 0.08838834764831845f;  // 1/sqrt(128)
        #pragma unroll
        for (int p = 0; p < 2; ++p)
            #pragma unroll
            for (int j = 0; j < 16; ++j) bufA[p][j][c] = (acc[p][j] + b0) * sc;
    }
    __syncthreads();

    // stage 6/7: per-channel softmax over K, res = sum_j attn*(vg+pos)
    #pragma unroll
    for (int p = 0; p < 2; ++p) {
        float l[16];
        float mx = -FLT_MAX;
        #pragma unroll
        for (int j = 0; j < 16; ++j) { l[j] = bufA[p][j][c]; mx = fmaxf(mx, l[j]); }
        float denom = 0.f;
        #pragma unroll
        for (int j = 0; j < 16; ++j) { l[j] = __expf(l[j] - mx); denom += l[j]; }
        float inv = 1.f / denom;
        float r = 0.f;
        #pragma unroll
        for (int j = 0; j < 16; ++j) {
            long g = (bofs + idxs[p][j]) * 128 + c;
            r = fmaf(l[j] * inv, v_ws[g] + bufP[p][j][c], r);
        }
        resl[p][c] = r;
    }
    __syncthreads();

    // stage 8: out = res @ fc2.T + b + feat  (residual), transposed store
    if (c < 6) {
        int p = c / 3, dp = c % 3;
        long pt = pbase + p;
        int n = (int)(pt & 8191);
        float a = fc2_b[dp];
        const float* w = fc2_w + dp*128;
        for (int cc = 0; cc < 128; ++cc) a = fmaf(w[cc], resl[p][cc], a);
        long o = ((long)b*3 + dp) * NPTS + n;
        out[o] = a + feat[o];
    }
}

// ---------------------------------------------------------------------------
extern "C" void kernel_launch(void* const* d_in, const int* in_sizes, int n_in,
                              void* d_out, int out_size, void* d_ws, size_t ws_size,
                              hipStream_t stream)
{
    const float* xyz   = (const float*)d_in[0];
    const float* feat  = (const float*)d_in[1];
    const float* fc1_w = (const float*)d_in[2];
    const float* fc1_b = (const float*)d_in[3];
    const float* fc2_w = (const float*)d_in[4];
    const float* fc2_b = (const float*)d_in[5];
    const float* d1_w  = (const float*)d_in[6];
    const float* d1_b  = (const float*)d_in[7];
    const float* d2_w  = (const float*)d_in[8];
    const float* d2_b  = (const float*)d_in[9];
    const float* g1_w  = (const float*)d_in[10];
    const float* g1_b  = (const float*)d_in[11];
    const float* g2_w  = (const float*)d_in[12];
    const float* g2_b  = (const float*)d_in[13];
    const float* wq_w  = (const float*)d_in[14];
    const float* wk_w  = (const float*)d_in[15];
    const float* wv_w  = (const float*)d_in[16];
    float* out = (float*)d_out;

    float* q_ws = (float*)d_ws;                       // 16384*128 f32
    float* k_ws = q_ws + (long)16384*128;
    float* v_ws = k_ws + (long)16384*128;
    int*  knn_ws = (int*)(v_ws + (long)16384*128);    // 16384*16 i32

    hipLaunchKernelGGL(proj_kernel, dim3(2048), dim3(128), 0, stream,
                       feat, fc1_w, fc1_b, wq_w, wk_w, wv_w, q_ws, k_ws, v_ws);
    hipLaunchKernelGGL(knn_kernel, dim3(1024), dim3(128), 0, stream, xyz, knn_ws);
    hipLaunchKernelGGL(attn_kernel, dim3(8192), dim3(128), 0, stream,
                       xyz, feat, d1_w, d1_b, d2_w, d2_b, g1_w, g1_b, g2_w, g2_b,
                       fc2_w, fc2_b, q_ws, k_ws, v_ws, knn_ws, out);
}

// Round 2
// 608.829 us; speedup vs baseline: 1.9772x; 1.9772x over previous
//
#include <hip/hip_runtime.h>
#include <cfloat>

#define NPTS 8192

typedef __attribute__((ext_vector_type(8))) short short8;
typedef __attribute__((ext_vector_type(4))) short short4v;
typedef __attribute__((ext_vector_type(4))) float f32x4;

__device__ inline unsigned short f2bf(float f) {
    unsigned u = __builtin_bit_cast(unsigned, f);
    u += 0x7fffu + ((u >> 16) & 1u);
    return (unsigned short)(u >> 16);
}
__device__ inline float bf2f(unsigned short h) {
    unsigned u = ((unsigned)h) << 16;
    return __builtin_bit_cast(float, u);
}

// ---------------------------------------------------------------------------
// Kernel 0: convert d2_w/g1_w/g2_w (fp32 128x128) -> bf16 in ws
// ---------------------------------------------------------------------------
__global__ void wconv_kernel(const float* __restrict__ d2_w,
                             const float* __restrict__ g1_w,
                             const float* __restrict__ g2_w,
                             unsigned short* __restrict__ wd2,
                             unsigned short* __restrict__ wg1,
                             unsigned short* __restrict__ wg2)
{
    int i = blockIdx.x * 256 + threadIdx.x;          // 0 .. 49151
    int sel = i >> 14, off = i & 16383;
    const float* s = (sel == 0) ? d2_w : (sel == 1) ? g1_w : g2_w;
    unsigned short* d = (sel == 0) ? wd2 : (sel == 1) ? wg1 : wg2;
    d[off] = f2bf(s[off]);
}

// ---------------------------------------------------------------------------
// Kernel 1: x = fc1(feat); q,k,v = x @ {wq,wk,wv}.T  -> bf16 outputs
// ---------------------------------------------------------------------------
__global__ __launch_bounds__(128, 2)
void proj_kernel(const float* __restrict__ feat,
                 const float* __restrict__ fc1_w, const float* __restrict__ fc1_b,
                 const float* __restrict__ wq, const float* __restrict__ wk,
                 const float* __restrict__ wv,
                 unsigned short* __restrict__ qb, unsigned short* __restrict__ kbuf,
                 unsigned short* __restrict__ vbuf)
{
    __shared__ float fl[8][3];
    __shared__ float xl[8][128];
    const int c = threadIdx.x;
    const long base = (long)blockIdx.x * 8;

    if (c < 24) {
        int p = c / 3, d = c % 3;
        long pt = base + p;
        int b = (int)(pt >> 13), n = (int)(pt & 8191);
        fl[p][d] = feat[((long)b * 3 + d) * NPTS + n];
    }
    __syncthreads();

    float w0 = fc1_w[c*3+0], w1 = fc1_w[c*3+1], w2 = fc1_w[c*3+2], b0 = fc1_b[c];
    #pragma unroll
    for (int p = 0; p < 8; ++p)
        xl[p][c] = fmaf(w0, fl[p][0], fmaf(w1, fl[p][1], fmaf(w2, fl[p][2], b0)));
    __syncthreads();

    float aq[8], ak[8], av[8];
    #pragma unroll
    for (int p = 0; p < 8; ++p) { aq[p] = 0.f; ak[p] = 0.f; av[p] = 0.f; }

    const float4* wq4 = (const float4*)(wq + c*128);
    const float4* wk4 = (const float4*)(wk + c*128);
    const float4* wv4 = (const float4*)(wv + c*128);
    for (int i4 = 0; i4 < 32; ++i4) {
        float4 a = wq4[i4], bw = wk4[i4], cw = wv4[i4];
        #pragma unroll
        for (int p = 0; p < 8; ++p) {
            float4 x = *(const float4*)&xl[p][i4*4];
            aq[p] = fmaf(a.x,x.x, fmaf(a.y,x.y, fmaf(a.z,x.z, fmaf(a.w,x.w, aq[p]))));
            ak[p] = fmaf(bw.x,x.x,fmaf(bw.y,x.y,fmaf(bw.z,x.z,fmaf(bw.w,x.w, ak[p]))));
            av[p] = fmaf(cw.x,x.x,fmaf(cw.y,x.y,fmaf(cw.z,x.z,fmaf(cw.w,x.w, av[p]))));
        }
    }
    #pragma unroll
    for (int p = 0; p < 8; ++p) {
        long pt = base + p;
        qb[pt*128 + c]   = f2bf(aq[p]);
        kbuf[pt*128 + c] = f2bf(ak[p]);
        vbuf[pt*128 + c] = f2bf(av[p]);
    }
}

// ---------------------------------------------------------------------------
// Kernel 2: brute-force KNN. 64 queries/block (512 thr), 8 threads/query,
// xyz staged fully in LDS; seeded top-16; ring+drain; rank merge.
// ---------------------------------------------------------------------------
__global__ __launch_bounds__(512, 1)
void knn_kernel(const float* __restrict__ xyz, int* __restrict__ knn)
{
    __shared__ float sx[24576];          // x[8192] y[8192] z[8192]; reused for merge
    __shared__ float ringd[512 * 9];
    __shared__ int   ringi[512 * 9];

    const int t  = threadIdx.x;
    const int ql = t >> 3, s = t & 7;
    const long qpt = (long)blockIdx.x * 64 + ql;
    const int b = (int)(qpt >> 13), n = (int)(qpt & 8191);

    {   // stage xyz (one batch) into LDS, float4
        const float4* src = (const float4*)(xyz + (long)b * 3 * NPTS);
        float4* dst = (float4*)sx;
        for (int i = t; i < 6144; i += 512) dst[i] = src[i];
    }
    __syncthreads();

    const float qx = sx[n], qy = sx[8192 + n], qz = sx[16384 + n];

    float ad[16];
    int   ai[16];
    #pragma unroll
    for (int i = 0; i < 16; ++i) { ad[i] = FLT_MAX; ai[i] = -1; }
    int wcnt = 0;

    auto insert16 = [&](float d, int idx) {
        bool hi = true;
        #pragma unroll
        for (int sl = 15; sl >= 1; --sl) {
            bool sw = d < ad[sl-1];
            float nd = sw ? ad[sl-1] : (hi ? d   : ad[sl]);
            int   ni = sw ? ai[sl-1] : (hi ? idx : ai[sl]);
            ad[sl] = nd; ai[sl] = ni;
            hi = hi && sw;
        }
        ad[0] = hi ? d   : ad[0];
        ai[0] = hi ? idx : ai[0];
    };
    auto drain = [&]() {
        for (int w = 0; w < wcnt; ++w) {
            float d = ringd[t*9 + w]; int idx = ringi[t*9 + w];
            if (d < ad[15]) insert16(d, idx);
        }
        wcnt = 0;
    };

    // seed with first 16 candidates (uniform, no divergence)
    #pragma unroll
    for (int it = 0; it < 16; ++it) {
        int m = s + 8*it;
        float dx = qx - sx[m], dy = qy - sx[8192+m], dz = qz - sx[16384+m];
        insert16(fmaf(dx,dx, fmaf(dy,dy, dz*dz)), m);
    }
    // stream the rest with live threshold
    for (int it = 16; it < 1024; ++it) {
        int m = s + 8*it;
        float dx = qx - sx[m], dy = qy - sx[8192+m], dz = qz - sx[16384+m];
        float d = fmaf(dx, dx, fmaf(dy, dy, dz*dz));
        if (d < ad[15]) { ringd[t*9 + wcnt] = d; ringi[t*9 + wcnt] = m; ++wcnt; }
        if (__any(wcnt >= 8)) drain();
    }
    drain();
    __syncthreads();   // done with sx as coords

    // merge: reuse sx region. dl[64][129], il[64][129]
    float* dl = sx;
    int*   il = (int*)(sx + 64*129);
    #pragma unroll
    for (int i = 0; i < 16; ++i) { dl[ql*129 + s*16 + i] = ad[i]; il[ql*129 + s*16 + i] = ai[i]; }
    __syncthreads();

    #pragma unroll
    for (int i = 0; i < 16; ++i) {
        float dk = ad[i]; int ik = ai[i];
        int rank = 0;
        for (int j = 0; j < 128; ++j) {
            float dj = dl[ql*129 + j];
            rank += ((dj < dk) || (dj == dk && il[ql*129 + j] < ik)) ? 1 : 0;
        }
        if (rank < 16) knn[qpt*16 + rank] = ik;
    }
}

// ---------------------------------------------------------------------------
// Kernel 3: fused attention, MFMA 16x16x32 bf16.
// 256 threads (4 waves), 8 points/block, wave owns 2 m-tiles (= 2 points).
// ---------------------------------------------------------------------------
#define HS 136   // bf16 row stride for hbuf/vpb (b128-aligned, 2-way banks)

__global__ __launch_bounds__(256, 2)
void attn_kernel(const float* __restrict__ xyz, const float* __restrict__ feat,
                 const float* __restrict__ d1_w, const float* __restrict__ d1_b,
                 const float* __restrict__ d2_b, const float* __restrict__ g1_b,
                 const float* __restrict__ g2_b,
                 const float* __restrict__ fc2_w, const float* __restrict__ fc2_b,
                 const unsigned short* __restrict__ qb,
                 const unsigned short* __restrict__ kb,
                 const unsigned short* __restrict__ vb,
                 const unsigned short* __restrict__ wd2,
                 const unsigned short* __restrict__ wg1,
                 const unsigned short* __restrict__ wg2,
                 const int* __restrict__ knn, float* __restrict__ out)
{
    __shared__ unsigned short hbuf[128 * HS];   // h1 -> h -> gh   (A operand)
    __shared__ unsigned short vpb [128 * HS];   // v  -> v + pos
    __shared__ unsigned short qsh [8 * 128];
    __shared__ float relb[128 * 4];
    __shared__ float resl[8 * 128];
    __shared__ int   idxs[128];

    const int t    = threadIdx.x;
    const int wave = t >> 6, lane = t & 63;
    const int quad = lane >> 4, l15 = lane & 15;
    const long pbase = (long)blockIdx.x * 8;
    const int b = (int)(pbase >> 13);
    const long bofs = (long)b * NPTS;

    // ---- stage knn indices ----
    if (t < 128) idxs[t] = knn[(pbase + (t >> 4)) * 16 + (t & 15)];
    __syncthreads();

    // ---- stage q (bf16), rel, gather v (bf16) ----
    {   // qsh: 1024 ushorts, short4 copies
        const short4v* src = (const short4v*)(qb + pbase * 128);
        short4v* dst = (short4v*)qsh;
        dst[t] = src[t];
    }
    if (t < 128) {
        int r = t;
        int nn = (int)((pbase + (r >> 4)) & 8191);
        int m = idxs[r];
        const float* xg = xyz + (long)b * 3 * NPTS;
        relb[r*4+0] = xg[nn]        - xg[m];
        relb[r*4+1] = xg[NPTS+nn]   - xg[NPTS+m];
        relb[r*4+2] = xg[2*NPTS+nn] - xg[2*NPTS+m];
    }
    {   // v gather: 128 rows x 16 chunks of 8 bf16
        for (int l = t; l < 2048; l += 256) {
            int row = l >> 4, c8 = l & 15;
            const short8* src = (const short8*)(vb + (size_t)(bofs + idxs[row]) * 128 + c8 * 8);
            *(short8*)&vpb[row * HS + c8 * 8] = *src;
        }
    }
    // ---- kg gather into registers (scattered, issued early) ----
    unsigned short kgu[2][4][8];
    #pragma unroll
    for (int mt = 0; mt < 2; ++mt)
        #pragma unroll
        for (int r = 0; r < 4; ++r) {
            int R = (wave*2 + mt)*16 + quad*4 + r;
            const unsigned short* kp = kb + (size_t)(bofs + idxs[R]) * 128 + l15;
            #pragma unroll
            for (int n0 = 0; n0 < 8; ++n0) kgu[mt][r][n0] = kp[n0 * 16];
        }
    __syncthreads();

    // ---- h1 = relu(rel @ d1.T + b) -> hbuf (cooperative: thread owns col c) ----
    {
        int c = t & 127, rb = t >> 7;
        float w0 = d1_w[c*3], w1 = d1_w[c*3+1], w2 = d1_w[c*3+2], b0 = d1_b[c];
        #pragma unroll
        for (int i = 0; i < 64; ++i) {
            int row = rb + 2*i;
            float v = fmaf(w0, relb[row*4+0], fmaf(w1, relb[row*4+1], fmaf(w2, relb[row*4+2], b0)));
            hbuf[row * HS + c] = f2bf(fmaxf(v, 0.f));
        }
    }
    __syncthreads();

    const int wrow0 = wave * 32;          // first row of this wave's 2 m-tiles
    short8 A[2][4];
    f32x4 acc[2];

    auto loadA = [&]() {
        #pragma unroll
        for (int mt = 0; mt < 2; ++mt)
            #pragma unroll
            for (int kk = 0; kk < 4; ++kk)
                A[mt][kk] = *(const short8*)&hbuf[(wrow0 + mt*16 + l15) * HS + kk*32 + quad*8];
    };

    // ================= GEMM 1: pos = h1 @ d2.T + b; h = q - kg + pos; vp += pos
    loadA();
    #pragma unroll
    for (int n0 = 0; n0 < 8; ++n0) {
        const unsigned short* wp = wd2 + (n0*16 + l15) * 128 + quad*8;
        short8 B0 = *(const short8*)(wp);
        short8 B1 = *(const short8*)(wp + 32);
        short8 B2 = *(const short8*)(wp + 64);
        short8 B3 = *(const short8*)(wp + 96);
        acc[0] = (f32x4){0.f,0.f,0.f,0.f};
        acc[1] = (f32x4){0.f,0.f,0.f,0.f};
        #pragma unroll
        for (int mt = 0; mt < 2; ++mt) {
            acc[mt] = __builtin_amdgcn_mfma_f32_16x16x32_bf16(A[mt][0], B0, acc[mt], 0, 0, 0);
            acc[mt] = __builtin_amdgcn_mfma_f32_16x16x32_bf16(A[mt][1], B1, acc[mt], 0, 0, 0);
            acc[mt] = __builtin_amdgcn_mfma_f32_16x16x32_bf16(A[mt][2], B2, acc[mt], 0, 0, 0);
            acc[mt] = __builtin_amdgcn_mfma_f32_16x16x32_bf16(A[mt][3], B3, acc[mt], 0, 0, 0);
        }
        int c = n0*16 + l15;
        float bb = d2_b[c];
        #pragma unroll
        for (int mt = 0; mt < 2; ++mt) {
            float qv = bf2f(qsh[(wave*2 + mt)*128 + c]);
            #pragma unroll
            for (int r = 0; r < 4; ++r) {
                int row = wrow0 + mt*16 + quad*4 + r;
                float pos = acc[mt][r] + bb;
                float h = qv - bf2f(kgu[mt][r][n0]) + pos;
                hbuf[row * HS + c] = f2bf(h);
                vpb[row * HS + c] = f2bf(bf2f(vpb[row * HS + c]) + pos);
            }
        }
    }

    // ================= GEMM 2: gh = relu(h @ g1.T + b)
    loadA();
    #pragma unroll
    for (int n0 = 0; n0 < 8; ++n0) {
        const unsigned short* wp = wg1 + (n0*16 + l15) * 128 + quad*8;
        short8 B0 = *(const short8*)(wp);
        short8 B1 = *(const short8*)(wp + 32);
        short8 B2 = *(const short8*)(wp + 64);
        short8 B3 = *(const short8*)(wp + 96);
        acc[0] = (f32x4){0.f,0.f,0.f,0.f};
        acc[1] = (f32x4){0.f,0.f,0.f,0.f};
        #pragma unroll
        for (int mt = 0; mt < 2; ++mt) {
            acc[mt] = __builtin_amdgcn_mfma_f32_16x16x32_bf16(A[mt][0], B0, acc[mt], 0, 0, 0);
            acc[mt] = __builtin_amdgcn_mfma_f32_16x16x32_bf16(A[mt][1], B1, acc[mt], 0, 0, 0);
            acc[mt] = __builtin_amdgcn_mfma_f32_16x16x32_bf16(A[mt][2], B2, acc[mt], 0, 0, 0);
            acc[mt] = __builtin_amdgcn_mfma_f32_16x16x32_bf16(A[mt][3], B3, acc[mt], 0, 0, 0);
        }
        int c = n0*16 + l15;
        float bb = g1_b[c];
        #pragma unroll
        for (int mt = 0; mt < 2; ++mt)
            #pragma unroll
            for (int r = 0; r < 4; ++r) {
                int row = wrow0 + mt*16 + quad*4 + r;
                hbuf[row * HS + c] = f2bf(fmaxf(acc[mt][r] + bb, 0.f));
            }
    }

    // ================= GEMM 3: logits = (gh @ g2.T + b)/sqrt(128); softmax over
    // the 16 rows of each m-tile per column; res = sum attn * vp
    loadA();
    const float sc = 0.08838834764831845f;
    #pragma unroll
    for (int n0 = 0; n0 < 8; ++n0) {
        const unsigned short* wp = wg2 + (n0*16 + l15) * 128 + quad*8;
        short8 B0 = *(const short8*)(wp);
        short8 B1 = *(const short8*)(wp + 32);
        short8 B2 = *(const short8*)(wp + 64);
        short8 B3 = *(const short8*)(wp + 96);
        acc[0] = (f32x4){0.f,0.f,0.f,0.f};
        acc[1] = (f32x4){0.f,0.f,0.f,0.f};
        #pragma unroll
        for (int mt = 0; mt < 2; ++mt) {
            acc[mt] = __builtin_amdgcn_mfma_f32_16x16x32_bf16(A[mt][0], B0, acc[mt], 0, 0, 0);
            acc[mt] = __builtin_amdgcn_mfma_f32_16x16x32_bf16(A[mt][1], B1, acc[mt], 0, 0, 0);
            acc[mt] = __builtin_amdgcn_mfma_f32_16x16x32_bf16(A[mt][2], B2, acc[mt], 0, 0, 0);
            acc[mt] = __builtin_amdgcn_mfma_f32_16x16x32_bf16(A[mt][3], B3, acc[mt], 0, 0, 0);
        }
        int c = n0*16 + l15;
        float bb = g2_b[c];
        #pragma unroll
        for (int mt = 0; mt < 2; ++mt) {
            float e0 = (acc[mt][0] + bb) * sc;
            float e1 = (acc[mt][1] + bb) * sc;
            float e2 = (acc[mt][2] + bb) * sc;
            float e3 = (acc[mt][3] + bb) * sc;
            float mx = fmaxf(fmaxf(e0, e1), fmaxf(e2, e3));
            mx = fmaxf(mx, __shfl_xor(mx, 16));
            mx = fmaxf(mx, __shfl_xor(mx, 32));
            e0 = __expf(e0 - mx); e1 = __expf(e1 - mx);
            e2 = __expf(e2 - mx); e3 = __expf(e3 - mx);
            float ssum = e0 + e1 + e2 + e3;
            ssum += __shfl_xor(ssum, 16);
            ssum += __shfl_xor(ssum, 32);
            int rowb = (wrow0 + mt*16 + quad*4) * HS + c;
            float p = e0 * bf2f(vpb[rowb])
                    + e1 * bf2f(vpb[rowb + HS])
                    + e2 * bf2f(vpb[rowb + 2*HS])
                    + e3 * bf2f(vpb[rowb + 3*HS]);
            p += __shfl_xor(p, 16);
            p += __shfl_xor(p, 32);
            if (quad == 0) resl[(wave*2 + mt)*128 + c] = p / ssum;
        }
    }
    __syncthreads();

    // ---- epilogue: out = res @ fc2.T + b + feat ----
    {
        int pt = t >> 5, j = t & 31;
        #pragma unroll
        for (int dp = 0; dp < 3; ++dp) {
            float part = 0.f;
            #pragma unroll
            for (int i = 0; i < 4; ++i) {
                int cc = j + 32*i;
                part = fmaf(fc2_w[dp*128 + cc], resl[pt*128 + cc], part);
            }
            part += __shfl_down(part, 16, 32);
            part += __shfl_down(part, 8, 32);
            part += __shfl_down(part, 4, 32);
            part += __shfl_down(part, 2, 32);
            part += __shfl_down(part, 1, 32);
            if (j == 0) {
                int nn = (int)((pbase + pt) & 8191);
                long o = ((long)b*3 + dp) * NPTS + nn;
                out[o] = part + fc2_b[dp] + feat[o];
            }
        }
    }
}

// ---------------------------------------------------------------------------
extern "C" void kernel_launch(void* const* d_in, const int* in_sizes, int n_in,
                              void* d_out, int out_size, void* d_ws, size_t ws_size,
                              hipStream_t stream)
{
    const float* xyz   = (const float*)d_in[0];
    const float* feat  = (const float*)d_in[1];
    const float* fc1_w = (const float*)d_in[2];
    const float* fc1_b = (const float*)d_in[3];
    const float* fc2_w = (const float*)d_in[4];
    const float* fc2_b = (const float*)d_in[5];
    const float* d1_w  = (const float*)d_in[6];
    const float* d1_b  = (const float*)d_in[7];
    const float* d2_w  = (const float*)d_in[8];
    const float* d2_b  = (const float*)d_in[9];
    const float* g1_w  = (const float*)d_in[10];
    const float* g1_b  = (const float*)d_in[11];
    const float* g2_w  = (const float*)d_in[12];
    const float* g2_b  = (const float*)d_in[13];
    const float* wq_w  = (const float*)d_in[14];
    const float* wk_w  = (const float*)d_in[15];
    const float* wv_w  = (const float*)d_in[16];
    float* out = (float*)d_out;

    unsigned short* qb  = (unsigned short*)d_ws;      // 16384*128 bf16
    unsigned short* kb  = qb + (size_t)16384*128;
    unsigned short* vb  = kb + (size_t)16384*128;
    unsigned short* wd2 = vb + (size_t)16384*128;     // 128*128 bf16 each
    unsigned short* wg1 = wd2 + 16384;
    unsigned short* wg2 = wg1 + 16384;
    int* knn_ws = (int*)(wg2 + 16384);                // 16384*16 i32

    hipLaunchKernelGGL(wconv_kernel, dim3(192), dim3(256), 0, stream,
                       d2_w, g1_w, g2_w, wd2, wg1, wg2);
    hipLaunchKernelGGL(proj_kernel, dim3(2048), dim3(128), 0, stream,
                       feat, fc1_w, fc1_b, wq_w, wk_w, wv_w, qb, kb, vb);
    hipLaunchKernelGGL(knn_kernel, dim3(256), dim3(512), 0, stream, xyz, knn_ws);
    hipLaunchKernelGGL(attn_kernel, dim3(2048), dim3(256), 0, stream,
                       xyz, feat, d1_w, d1_b, d2_b, g1_b, g2_b, fc2_w, fc2_b,
                       qb, kb, vb, wd2, wg1, wg2, knn_ws, out);
}

// Round 3
// 590.407 us; speedup vs baseline: 2.0389x; 1.0312x over previous
//
#include <hip/hip_runtime.h>
#include <cfloat>

#define NPTS 8192

typedef __attribute__((ext_vector_type(8))) short short8;
typedef __attribute__((ext_vector_type(4))) short short4v;
typedef __attribute__((ext_vector_type(4))) float f32x4;

__device__ inline unsigned short f2bf(float f) {
    unsigned u = __builtin_bit_cast(unsigned, f);
    u += 0x7fffu + ((u >> 16) & 1u);
    return (unsigned short)(u >> 16);
}
__device__ inline float bf2f(unsigned short h) {
    unsigned u = ((unsigned)h) << 16;
    return __builtin_bit_cast(float, u);
}

// ---------------------------------------------------------------------------
// Kernel 0: convert d2_w/g1_w/g2_w (fp32 128x128) -> bf16 in ws
// ---------------------------------------------------------------------------
__global__ void wconv_kernel(const float* __restrict__ d2_w,
                             const float* __restrict__ g1_w,
                             const float* __restrict__ g2_w,
                             unsigned short* __restrict__ wd2,
                             unsigned short* __restrict__ wg1,
                             unsigned short* __restrict__ wg2)
{
    int i = blockIdx.x * 256 + threadIdx.x;          // 0 .. 49151
    int sel = i >> 14, off = i & 16383;
    const float* s = (sel == 0) ? d2_w : (sel == 1) ? g1_w : g2_w;
    unsigned short* d = (sel == 0) ? wd2 : (sel == 1) ? wg1 : wg2;
    d[off] = f2bf(s[off]);
}

// ---------------------------------------------------------------------------
// Kernel 1: x = fc1(feat); q,k,v = x @ {wq,wk,wv}.T  -> bf16 outputs
// ---------------------------------------------------------------------------
__global__ __launch_bounds__(128, 2)
void proj_kernel(const float* __restrict__ feat,
                 const float* __restrict__ fc1_w, const float* __restrict__ fc1_b,
                 const float* __restrict__ wq, const float* __restrict__ wk,
                 const float* __restrict__ wv,
                 unsigned short* __restrict__ qb, unsigned short* __restrict__ kbuf,
                 unsigned short* __restrict__ vbuf)
{
    __shared__ float fl[8][3];
    __shared__ float xl[8][128];
    const int c = threadIdx.x;
    const long base = (long)blockIdx.x * 8;

    if (c < 24) {
        int p = c / 3, d = c % 3;
        long pt = base + p;
        int b = (int)(pt >> 13), n = (int)(pt & 8191);
        fl[p][d] = feat[((long)b * 3 + d) * NPTS + n];
    }
    __syncthreads();

    float w0 = fc1_w[c*3+0], w1 = fc1_w[c*3+1], w2 = fc1_w[c*3+2], b0 = fc1_b[c];
    #pragma unroll
    for (int p = 0; p < 8; ++p)
        xl[p][c] = fmaf(w0, fl[p][0], fmaf(w1, fl[p][1], fmaf(w2, fl[p][2], b0)));
    __syncthreads();

    float aq[8], ak[8], av[8];
    #pragma unroll
    for (int p = 0; p < 8; ++p) { aq[p] = 0.f; ak[p] = 0.f; av[p] = 0.f; }

    const float4* wq4 = (const float4*)(wq + c*128);
    const float4* wk4 = (const float4*)(wk + c*128);
    const float4* wv4 = (const float4*)(wv + c*128);
    for (int i4 = 0; i4 < 32; ++i4) {
        float4 a = wq4[i4], bw = wk4[i4], cw = wv4[i4];
        #pragma unroll
        for (int p = 0; p < 8; ++p) {
            float4 x = *(const float4*)&xl[p][i4*4];
            aq[p] = fmaf(a.x,x.x, fmaf(a.y,x.y, fmaf(a.z,x.z, fmaf(a.w,x.w, aq[p]))));
            ak[p] = fmaf(bw.x,x.x,fmaf(bw.y,x.y,fmaf(bw.z,x.z,fmaf(bw.w,x.w, ak[p]))));
            av[p] = fmaf(cw.x,x.x,fmaf(cw.y,x.y,fmaf(cw.z,x.z,fmaf(cw.w,x.w, av[p]))));
        }
    }
    #pragma unroll
    for (int p = 0; p < 8; ++p) {
        long pt = base + p;
        qb[pt*128 + c]   = f2bf(aq[p]);
        kbuf[pt*128 + c] = f2bf(ak[p]);
        vbuf[pt*128 + c] = f2bf(av[p]);
    }
}

// ---------------------------------------------------------------------------
// Kernel 2a: candidate prep — pack (x,y,z,||p||^2) float4 per point
// ---------------------------------------------------------------------------
__global__ void candprep_kernel(const float* __restrict__ xyz,
                                float4* __restrict__ cand)
{
    int i = blockIdx.x * 256 + threadIdx.x;          // 0..16383
    int b = i >> 13, n = i & 8191;
    const float* xg = xyz + (long)b * 3 * NPTS;
    float x = xg[n], y = xg[NPTS + n], z = xg[2*NPTS + n];
    float4 c; c.x = x; c.y = y; c.z = z;
    c.w = fmaf(x, x, fmaf(y, y, z * z));
    cand[i] = c;
}

// ---------------------------------------------------------------------------
// Kernel 2b: KNN partial — 1 lane per query, wave-uniform candidate stream
// (scalar loads). 256 queries/block, candidate chunk = blockIdx&3 (2048 cands).
// d' = ||b||^2 - 2 q.b  (== ||q-b||^2 - ||q||^2, order-preserving per query)
// ---------------------------------------------------------------------------
#define CHUNK 2048
#define RINGN 12
#define DRTH 8

__global__ __launch_bounds__(256, 4)
void knn_part_kernel(const float4* __restrict__ cand,
                     float* __restrict__ part_d, int* __restrict__ part_i)
{
    __shared__ float2 ring[256 * RINGN];   // 24 KB

    const int t = threadIdx.x;
    const int qsg = blockIdx.x >> 2;           // 0..63
    const int ck  = blockIdx.x & 3;            // candidate chunk
    const long q  = (long)qsg * 256 + t;       // global query id
    const int b   = (int)(q >> 13);
    const int n   = (int)(q & 8191);

    float4 qc = cand[((long)b << 13) + n];
    const float qx2 = -2.f * qc.x, qy2 = -2.f * qc.y, qz2 = -2.f * qc.z;
    const float4* cp = cand + ((long)b << 13) + ck * CHUNK;  // wave-uniform

    float ad[16];
    int   ai[16];
    #pragma unroll
    for (int i = 0; i < 16; ++i) { ad[i] = FLT_MAX; ai[i] = -1; }
    int wcnt = 0;

    auto insert16 = [&](float d, int idx) {
        bool hi = true;
        #pragma unroll
        for (int sl = 15; sl >= 1; --sl) {
            bool sw = d < ad[sl-1];
            float nd = sw ? ad[sl-1] : (hi ? d   : ad[sl]);
            int   ni = sw ? ai[sl-1] : (hi ? idx : ai[sl]);
            ad[sl] = nd; ai[sl] = ni;
            hi = hi && sw;
        }
        ad[0] = hi ? d   : ad[0];
        ai[0] = hi ? idx : ai[0];
    };
    auto drain = [&]() {
        for (int w = 0; w < wcnt; ++w) {
            float2 e = ring[t * RINGN + w];
            if (e.x < ad[15]) insert16(e.x, __builtin_bit_cast(int, e.y));
        }
        wcnt = 0;
    };

    // seed: first 16 candidates, unconditional sorted insert
    #pragma unroll
    for (int m = 0; m < 16; ++m) {
        float4 c = cp[m];
        float d = fmaf(qx2, c.x, fmaf(qy2, c.y, fmaf(qz2, c.z, c.w)));
        insert16(d, ck * CHUNK + m);
    }
    // stream remainder, unrolled x4, ring-buffered inserts
    for (int m = 16; m < CHUNK; m += 4) {
        #pragma unroll
        for (int u = 0; u < 4; ++u) {
            float4 c = cp[m + u];
            float d = fmaf(qx2, c.x, fmaf(qy2, c.y, fmaf(qz2, c.z, c.w)));
            if (d < ad[15]) {
                float2 e; e.x = d; e.y = __builtin_bit_cast(float, ck * CHUNK + m + u);
                ring[t * RINGN + wcnt] = e;
                ++wcnt;
            }
        }
        if (__any(wcnt >= DRTH)) drain();
    }
    drain();

    // write exact chunk top-16
    #pragma unroll
    for (int i = 0; i < 16; ++i) {
        part_d[(q * 4 + ck) * 16 + i] = ad[i];
        part_i[(q * 4 + ck) * 16 + i] = ai[i];
    }
}

// ---------------------------------------------------------------------------
// Kernel 2c: merge 4 partial top-16 -> final top-16 (rank select, idx ties)
// ---------------------------------------------------------------------------
__global__ __launch_bounds__(256, 4)
void knn_merge_kernel(const float* __restrict__ part_d,
                      const int* __restrict__ part_i, int* __restrict__ knn)
{
    __shared__ float sd[4][64];
    __shared__ int   si[4][64];
    const int t = threadIdx.x;
    const int ql = t >> 6, e = t & 63;
    const long q = (long)blockIdx.x * 4 + ql;
    float d = part_d[q * 64 + e];
    int idx = part_i[q * 64 + e];
    sd[ql][e] = d; si[ql][e] = idx;
    __syncthreads();
    int rank = 0;
    #pragma unroll 8
    for (int j = 0; j < 64; ++j) {
        float dj = sd[ql][j];
        rank += ((dj < d) || (dj == d && si[ql][j] < idx)) ? 1 : 0;
    }
    if (rank < 16) knn[q * 16 + rank] = idx;
}

// ---------------------------------------------------------------------------
// Kernel 3: fused attention, MFMA 16x16x32 bf16.
// 256 threads (4 waves), 8 points/block, wave owns 2 m-tiles.
// hbuf: stride 128 + XOR swizzle (kills loadA 8-way conflict).
// pos kept in registers (packed bf16) — no vpb read-modify-write.
// ---------------------------------------------------------------------------
#define HS 136   // vpb row stride (bf16)

__device__ inline int hswz(int r, int c) {           // hbuf swizzled index
    return r * 128 + (c ^ ((r & 7) << 4));
}

__global__ __launch_bounds__(256, 2)
void attn_kernel(const float* __restrict__ xyz, const float* __restrict__ feat,
                 const float* __restrict__ d1_w, const float* __restrict__ d1_b,
                 const float* __restrict__ d2_b, const float* __restrict__ g1_b,
                 const float* __restrict__ g2_b,
                 const float* __restrict__ fc2_w, const float* __restrict__ fc2_b,
                 const unsigned short* __restrict__ qb,
                 const unsigned short* __restrict__ kb,
                 const unsigned short* __restrict__ vb,
                 const unsigned short* __restrict__ wd2,
                 const unsigned short* __restrict__ wg1,
                 const unsigned short* __restrict__ wg2,
                 const int* __restrict__ knn, float* __restrict__ out)
{
    __shared__ unsigned short hbuf[128 * 128];  // h1 -> h -> gh (swizzled)
    __shared__ unsigned short vpb [128 * HS];   // v (pure)
    __shared__ unsigned short qsh [8 * 128];
    __shared__ float relb[128 * 4];
    __shared__ float resl[8 * 128];
    __shared__ int   idxs[128];

    const int t    = threadIdx.x;
    const int wave = t >> 6, lane = t & 63;
    const int quad = lane >> 4, l15 = lane & 15;
    const long pbase = (long)blockIdx.x * 8;
    const int b = (int)(pbase >> 13);
    const long bofs = (long)b * NPTS;

    if (t < 128) idxs[t] = knn[(pbase + (t >> 4)) * 16 + (t & 15)];
    __syncthreads();

    {   // qsh staging
        const short4v* src = (const short4v*)(qb + pbase * 128);
        short4v* dst = (short4v*)qsh;
        dst[t] = src[t];
    }
    if (t < 128) {
        int r = t;
        int nn = (int)((pbase + (r >> 4)) & 8191);
        int m = idxs[r];
        const float* xg = xyz + (long)b * 3 * NPTS;
        relb[r*4+0] = xg[nn]        - xg[m];
        relb[r*4+1] = xg[NPTS+nn]   - xg[NPTS+m];
        relb[r*4+2] = xg[2*NPTS+nn] - xg[2*NPTS+m];
        relb[r*4+3] = 0.f;
    }
    {   // v gather: 128 rows x 16 chunks of 8 bf16
        for (int l = t; l < 2048; l += 256) {
            int row = l >> 4, c8 = l & 15;
            const short8* src = (const short8*)(vb + (size_t)(bofs + idxs[row]) * 128 + c8 * 8);
            *(short8*)&vpb[row * HS + c8 * 8] = *src;
        }
    }
    // kg gather into registers (scattered, issued early)
    unsigned short kgu[2][4][8];
    #pragma unroll
    for (int mt = 0; mt < 2; ++mt)
        #pragma unroll
        for (int r = 0; r < 4; ++r) {
            int R = (wave*2 + mt)*16 + quad*4 + r;
            const unsigned short* kp = kb + (size_t)(bofs + idxs[R]) * 128 + l15;
            #pragma unroll
            for (int n0 = 0; n0 < 8; ++n0) kgu[mt][r][n0] = kp[n0 * 16];
        }
    __syncthreads();

    // ---- h1 = relu(rel @ d1.T + b) -> hbuf, vectorized b128 writes ----
    {
        int c8 = t & 15, r0 = t >> 4;
        float w0[8], w1[8], w2[8], bb[8];
        #pragma unroll
        for (int k = 0; k < 8; ++k) {
            int c = c8*8 + k;
            w0[k] = d1_w[c*3]; w1[k] = d1_w[c*3+1]; w2[k] = d1_w[c*3+2];
            bb[k] = d1_b[c];
        }
        #pragma unroll
        for (int i = 0; i < 8; ++i) {
            int row = r0 + 16*i;
            float4 rl = *(const float4*)&relb[row*4];
            short8 hv;
            #pragma unroll
            for (int k = 0; k < 8; ++k) {
                float v = fmaf(w0[k], rl.x, fmaf(w1[k], rl.y, fmaf(w2[k], rl.z, bb[k])));
                hv[k] = (short)f2bf(fmaxf(v, 0.f));
            }
            *(short8*)&hbuf[hswz(row, c8*8)] = hv;
        }
    }
    __syncthreads();

    const int wrow0 = wave * 32;
    short8 A[2][4];
    f32x4 acc[2];

    auto loadA = [&]() {
        #pragma unroll
        for (int mt = 0; mt < 2; ++mt)
            #pragma unroll
            for (int kk = 0; kk < 4; ++kk)
                A[mt][kk] = *(const short8*)&hbuf[hswz(wrow0 + mt*16 + l15, kk*32 + quad*8)];
    };

    unsigned posp[2][8][2];   // packed bf16 pos fragments

    // ============ GEMM 1: pos = h1 @ d2.T + b; h = q - kg + pos ============
    loadA();
    #pragma unroll
    for (int n0 = 0; n0 < 8; ++n0) {
        const unsigned short* wp = wd2 + (n0*16 + l15) * 128 + quad*8;
        short8 B0 = *(const short8*)(wp);
        short8 B1 = *(const short8*)(wp + 32);
        short8 B2 = *(const short8*)(wp + 64);
        short8 B3 = *(const short8*)(wp + 96);
        acc[0] = (f32x4){0.f,0.f,0.f,0.f};
        acc[1] = (f32x4){0.f,0.f,0.f,0.f};
        #pragma unroll
        for (int mt = 0; mt < 2; ++mt) {
            acc[mt] = __builtin_amdgcn_mfma_f32_16x16x32_bf16(A[mt][0], B0, acc[mt], 0, 0, 0);
            acc[mt] = __builtin_amdgcn_mfma_f32_16x16x32_bf16(A[mt][1], B1, acc[mt], 0, 0, 0);
            acc[mt] = __builtin_amdgcn_mfma_f32_16x16x32_bf16(A[mt][2], B2, acc[mt], 0, 0, 0);
            acc[mt] = __builtin_amdgcn_mfma_f32_16x16x32_bf16(A[mt][3], B3, acc[mt], 0, 0, 0);
        }
        int c = n0*16 + l15;
        float bb = d2_b[c];
        #pragma unroll
        for (int mt = 0; mt < 2; ++mt) {
            float qv = bf2f(qsh[(wave*2 + mt)*128 + c]);
            float p0 = acc[mt][0] + bb, p1 = acc[mt][1] + bb;
            float p2 = acc[mt][2] + bb, p3 = acc[mt][3] + bb;
            posp[mt][n0][0] = (unsigned)f2bf(p0) | ((unsigned)f2bf(p1) << 16);
            posp[mt][n0][1] = (unsigned)f2bf(p2) | ((unsigned)f2bf(p3) << 16);
            int rb = wrow0 + mt*16 + quad*4;
            hbuf[hswz(rb+0, c)] = f2bf(qv - bf2f(kgu[mt][0][n0]) + p0);
            hbuf[hswz(rb+1, c)] = f2bf(qv - bf2f(kgu[mt][1][n0]) + p1);
            hbuf[hswz(rb+2, c)] = f2bf(qv - bf2f(kgu[mt][2][n0]) + p2);
            hbuf[hswz(rb+3, c)] = f2bf(qv - bf2f(kgu[mt][3][n0]) + p3);
        }
    }

    // ============ GEMM 2: gh = relu(h @ g1.T + b) ============
    loadA();
    #pragma unroll
    for (int n0 = 0; n0 < 8; ++n0) {
        const unsigned short* wp = wg1 + (n0*16 + l15) * 128 + quad*8;
        short8 B0 = *(const short8*)(wp);
        short8 B1 = *(const short8*)(wp + 32);
        short8 B2 = *(const short8*)(wp + 64);
        short8 B3 = *(const short8*)(wp + 96);
        acc[0] = (f32x4){0.f,0.f,0.f,0.f};
        acc[1] = (f32x4){0.f,0.f,0.f,0.f};
        #pragma unroll
        for (int mt = 0; mt < 2; ++mt) {
            acc[mt] = __builtin_amdgcn_mfma_f32_16x16x32_bf16(A[mt][0], B0, acc[mt], 0, 0, 0);
            acc[mt] = __builtin_amdgcn_mfma_f32_16x16x32_bf16(A[mt][1], B1, acc[mt], 0, 0, 0);
            acc[mt] = __builtin_amdgcn_mfma_f32_16x16x32_bf16(A[mt][2], B2, acc[mt], 0, 0, 0);
            acc[mt] = __builtin_amdgcn_mfma_f32_16x16x32_bf16(A[mt][3], B3, acc[mt], 0, 0, 0);
        }
        int c = n0*16 + l15;
        float bb = g1_b[c];
        #pragma unroll
        for (int mt = 0; mt < 2; ++mt) {
            int rb = wrow0 + mt*16 + quad*4;
            #pragma unroll
            for (int r = 0; r < 4; ++r)
                hbuf[hswz(rb+r, c)] = f2bf(fmaxf(acc[mt][r] + bb, 0.f));
        }
    }

    // ==== GEMM 3: logits -> softmax over K -> res = sum attn*(v+pos) ====
    loadA();
    const float sc = 0.08838834764831845f;
    #pragma unroll
    for (int n0 = 0; n0 < 8; ++n0) {
        const unsigned short* wp = wg2 + (n0*16 + l15) * 128 + quad*8;
        short8 B0 = *(const short8*)(wp);
        short8 B1 = *(const short8*)(wp + 32);
        short8 B2 = *(const short8*)(wp + 64);
        short8 B3 = *(const short8*)(wp + 96);
        acc[0] = (f32x4){0.f,0.f,0.f,0.f};
        acc[1] = (f32x4){0.f,0.f,0.f,0.f};
        #pragma unroll
        for (int mt = 0; mt < 2; ++mt) {
            acc[mt] = __builtin_amdgcn_mfma_f32_16x16x32_bf16(A[mt][0], B0, acc[mt], 0, 0, 0);
            acc[mt] = __builtin_amdgcn_mfma_f32_16x16x32_bf16(A[mt][1], B1, acc[mt], 0, 0, 0);
            acc[mt] = __builtin_amdgcn_mfma_f32_16x16x32_bf16(A[mt][2], B2, acc[mt], 0, 0, 0);
            acc[mt] = __builtin_amdgcn_mfma_f32_16x16x32_bf16(A[mt][3], B3, acc[mt], 0, 0, 0);
        }
        int c = n0*16 + l15;
        float bb = g2_b[c];
        #pragma unroll
        for (int mt = 0; mt < 2; ++mt) {
            float e0 = (acc[mt][0] + bb) * sc;
            float e1 = (acc[mt][1] + bb) * sc;
            float e2 = (acc[mt][2] + bb) * sc;
            float e3 = (acc[mt][3] + bb) * sc;
            float mx = fmaxf(fmaxf(e0, e1), fmaxf(e2, e3));
            mx = fmaxf(mx, __shfl_xor(mx, 16));
            mx = fmaxf(mx, __shfl_xor(mx, 32));
            e0 = __expf(e0 - mx); e1 = __expf(e1 - mx);
            e2 = __expf(e2 - mx); e3 = __expf(e3 - mx);
            float ssum = e0 + e1 + e2 + e3;
            ssum += __shfl_xor(ssum, 16);
            ssum += __shfl_xor(ssum, 32);
            float p0 = bf2f((unsigned short)(posp[mt][n0][0] & 0xffff));
            float p1 = bf2f((unsigned short)(posp[mt][n0][0] >> 16));
            float p2 = bf2f((unsigned short)(posp[mt][n0][1] & 0xffff));
            float p3 = bf2f((unsigned short)(posp[mt][n0][1] >> 16));
            int rowb = (wrow0 + mt*16 + quad*4) * HS + c;
            float p = e0 * (bf2f(vpb[rowb])        + p0)
                    + e1 * (bf2f(vpb[rowb + HS])   + p1)
                    + e2 * (bf2f(vpb[rowb + 2*HS]) + p2)
                    + e3 * (bf2f(vpb[rowb + 3*HS]) + p3);
            p += __shfl_xor(p, 16);
            p += __shfl_xor(p, 32);
            if (quad == 0) resl[(wave*2 + mt)*128 + c] = p / ssum;
        }
    }
    __syncthreads();

    // ---- epilogue: out = res @ fc2.T + b + feat ----
    {
        int pt = t >> 5, j = t & 31;
        #pragma unroll
        for (int dp = 0; dp < 3; ++dp) {
            float part = 0.f;
            #pragma unroll
            for (int i = 0; i < 4; ++i) {
                int cc = j + 32*i;
                part = fmaf(fc2_w[dp*128 + cc], resl[pt*128 + cc], part);
            }
            part += __shfl_down(part, 16, 32);
            part += __shfl_down(part, 8, 32);
            part += __shfl_down(part, 4, 32);
            part += __shfl_down(part, 2, 32);
            part += __shfl_down(part, 1, 32);
            if (j == 0) {
                int nn = (int)((pbase + pt) & 8191);
                long o = ((long)b*3 + dp) * NPTS + nn;
                out[o] = part + fc2_b[dp] + feat[o];
            }
        }
    }
}

// ---------------------------------------------------------------------------
extern "C" void kernel_launch(void* const* d_in, const int* in_sizes, int n_in,
                              void* d_out, int out_size, void* d_ws, size_t ws_size,
                              hipStream_t stream)
{
    const float* xyz   = (const float*)d_in[0];
    const float* feat  = (const float*)d_in[1];
    const float* fc1_w = (const float*)d_in[2];
    const float* fc1_b = (const float*)d_in[3];
    const float* fc2_w = (const float*)d_in[4];
    const float* fc2_b = (const float*)d_in[5];
    const float* d1_w  = (const float*)d_in[6];
    const float* d1_b  = (const float*)d_in[7];
    const float* d2_w  = (const float*)d_in[8];
    const float* d2_b  = (const float*)d_in[9];
    const float* g1_w  = (const float*)d_in[10];
    const float* g1_b  = (const float*)d_in[11];
    const float* g2_w  = (const float*)d_in[12];
    const float* g2_b  = (const float*)d_in[13];
    const float* wq_w  = (const float*)d_in[14];
    const float* wk_w  = (const float*)d_in[15];
    const float* wv_w  = (const float*)d_in[16];
    float* out = (float*)d_out;

    unsigned short* qb  = (unsigned short*)d_ws;      // 16384*128 bf16
    unsigned short* kb  = qb + (size_t)16384*128;
    unsigned short* vb  = kb + (size_t)16384*128;
    unsigned short* wd2 = vb + (size_t)16384*128;     // 128*128 bf16 each
    unsigned short* wg1 = wd2 + 16384;
    unsigned short* wg2 = wg1 + 16384;
    int*   knn_ws = (int*)(wg2 + 16384);              // 16384*16 i32
    float4* cand  = (float4*)(knn_ws + (size_t)16384*16);   // 16384 float4
    float* part_d = (float*)(cand + 16384);           // 16384*64 f32
    int*   part_i = (int*)(part_d + (size_t)16384*64);// 16384*64 i32

    hipLaunchKernelGGL(wconv_kernel, dim3(192), dim3(256), 0, stream,
                       d2_w, g1_w, g2_w, wd2, wg1, wg2);
    hipLaunchKernelGGL(candprep_kernel, dim3(64), dim3(256), 0, stream, xyz, cand);
    hipLaunchKernelGGL(knn_part_kernel, dim3(256), dim3(256), 0, stream,
                       cand, part_d, part_i);
    hipLaunchKernelGGL(knn_merge_kernel, dim3(4096), dim3(256), 0, stream,
                       part_d, part_i, knn_ws);
    hipLaunchKernelGGL(proj_kernel, dim3(2048), dim3(128), 0, stream,
                       feat, fc1_w, fc1_b, wq_w, wk_w, wv_w, qb, kb, vb);
    hipLaunchKernelGGL(attn_kernel, dim3(2048), dim3(256), 0, stream,
                       xyz, feat, d1_w, d1_b, d2_b, g1_b, g2_b, fc2_w, fc2_b,
                       qb, kb, vb, wd2, wg1, wg2, knn_ws, out);
}

// Round 4
// 514.583 us; speedup vs baseline: 2.3393x; 1.1474x over previous
//
#include <hip/hip_runtime.h>
#include <cfloat>

#define NPTS 8192

typedef __attribute__((ext_vector_type(8))) short short8;
typedef __attribute__((ext_vector_type(4))) short short4v;
typedef __attribute__((ext_vector_type(4))) float f32x4;

__device__ inline unsigned short f2bf(float f) {
    unsigned u = __builtin_bit_cast(unsigned, f);
    u += 0x7fffu + ((u >> 16) & 1u);
    return (unsigned short)(u >> 16);
}
__device__ inline float bf2f(unsigned short h) {
    unsigned u = ((unsigned)h) << 16;
    return __builtin_bit_cast(float, u);
}

// ---------------------------------------------------------------------------
// Kernel 0: convert d2_w/g1_w/g2_w (fp32 128x128) -> bf16 in ws
// ---------------------------------------------------------------------------
__global__ void wconv_kernel(const float* __restrict__ d2_w,
                             const float* __restrict__ g1_w,
                             const float* __restrict__ g2_w,
                             unsigned short* __restrict__ wd2,
                             unsigned short* __restrict__ wg1,
                             unsigned short* __restrict__ wg2)
{
    int i = blockIdx.x * 256 + threadIdx.x;          // 0 .. 49151
    int sel = i >> 14, off = i & 16383;
    const float* s = (sel == 0) ? d2_w : (sel == 1) ? g1_w : g2_w;
    unsigned short* d = (sel == 0) ? wd2 : (sel == 1) ? wg1 : wg2;
    d[off] = f2bf(s[off]);
}

// ---------------------------------------------------------------------------
// Kernel 1: x = fc1(feat); q,k,v = x @ {wq,wk,wv}.T  -> bf16 outputs
// ---------------------------------------------------------------------------
__global__ __launch_bounds__(128, 2)
void proj_kernel(const float* __restrict__ feat,
                 const float* __restrict__ fc1_w, const float* __restrict__ fc1_b,
                 const float* __restrict__ wq, const float* __restrict__ wk,
                 const float* __restrict__ wv,
                 unsigned short* __restrict__ qb, unsigned short* __restrict__ kbuf,
                 unsigned short* __restrict__ vbuf)
{
    __shared__ float fl[8][3];
    __shared__ float xl[8][128];
    const int c = threadIdx.x;
    const long base = (long)blockIdx.x * 8;

    if (c < 24) {
        int p = c / 3, d = c % 3;
        long pt = base + p;
        int b = (int)(pt >> 13), n = (int)(pt & 8191);
        fl[p][d] = feat[((long)b * 3 + d) * NPTS + n];
    }
    __syncthreads();

    float w0 = fc1_w[c*3+0], w1 = fc1_w[c*3+1], w2 = fc1_w[c*3+2], b0 = fc1_b[c];
    #pragma unroll
    for (int p = 0; p < 8; ++p)
        xl[p][c] = fmaf(w0, fl[p][0], fmaf(w1, fl[p][1], fmaf(w2, fl[p][2], b0)));
    __syncthreads();

    float aq[8], ak[8], av[8];
    #pragma unroll
    for (int p = 0; p < 8; ++p) { aq[p] = 0.f; ak[p] = 0.f; av[p] = 0.f; }

    const float4* wq4 = (const float4*)(wq + c*128);
    const float4* wk4 = (const float4*)(wk + c*128);
    const float4* wv4 = (const float4*)(wv + c*128);
    for (int i4 = 0; i4 < 32; ++i4) {
        float4 a = wq4[i4], bw = wk4[i4], cw = wv4[i4];
        #pragma unroll
        for (int p = 0; p < 8; ++p) {
            float4 x = *(const float4*)&xl[p][i4*4];
            aq[p] = fmaf(a.x,x.x, fmaf(a.y,x.y, fmaf(a.z,x.z, fmaf(a.w,x.w, aq[p]))));
            ak[p] = fmaf(bw.x,x.x,fmaf(bw.y,x.y,fmaf(bw.z,x.z,fmaf(bw.w,x.w, ak[p]))));
            av[p] = fmaf(cw.x,x.x,fmaf(cw.y,x.y,fmaf(cw.z,x.z,fmaf(cw.w,x.w, av[p]))));
        }
    }
    #pragma unroll
    for (int p = 0; p < 8; ++p) {
        long pt = base + p;
        qb[pt*128 + c]   = f2bf(aq[p]);
        kbuf[pt*128 + c] = f2bf(ak[p]);
        vbuf[pt*128 + c] = f2bf(av[p]);
    }
}

// ---------------------------------------------------------------------------
// Kernel 2a: candidate prep — pack (x,y,z,||p||^2) float4 per point
// ---------------------------------------------------------------------------
__global__ void candprep_kernel(const float* __restrict__ xyz,
                                float4* __restrict__ cand)
{
    int i = blockIdx.x * 256 + threadIdx.x;          // 0..16383
    int b = i >> 13, n = i & 8191;
    const float* xg = xyz + (long)b * 3 * NPTS;
    float x = xg[n], y = xg[NPTS + n], z = xg[2*NPTS + n];
    float4 c; c.x = x; c.y = y; c.z = z;
    c.w = fmaf(x, x, fmaf(y, y, z * z));
    cand[i] = c;
}

// ---------------------------------------------------------------------------
// Kernel 2b: KNN partial. 1 lane per query; candidates staged in LDS and
// broadcast-read (all lanes same addr, conflict-free). Software-pipelined
// groups of 8 for ILP; LDS ring + wave-synced drains for rare inserts.
// d' = ||b||^2 - 2 q.b  (order-preserving per query)
// ---------------------------------------------------------------------------
#define CHUNK 2048
#define RINGN 14
#define DRTH 6

__global__ __launch_bounds__(256, 1)
void knn_part_kernel(const float4* __restrict__ cand,
                     float* __restrict__ part_d, int* __restrict__ part_i)
{
    __shared__ float4 cl[CHUNK];            // 32 KB candidate chunk
    __shared__ float2 ring[256 * RINGN];    // 28 KB, stride 14 (2-way alias ok)

    const int t = threadIdx.x;
    const int qsg = blockIdx.x >> 2;           // 0..63
    const int ck  = blockIdx.x & 3;            // candidate chunk
    const long q  = (long)qsg * 256 + t;       // global query id
    const int b   = (int)(q >> 13);
    const int n   = (int)(q & 8191);

    // stage the chunk (coalesced float4)
    {
        const float4* src = cand + ((long)b << 13) + ck * CHUNK;
        for (int i = t; i < CHUNK; i += 256) cl[i] = src[i];
    }

    float4 qc = cand[((long)b << 13) + n];
    const float qx2 = -2.f * qc.x, qy2 = -2.f * qc.y, qz2 = -2.f * qc.z;
    __syncthreads();

    float ad[16];
    int   ai[16];
    #pragma unroll
    for (int i = 0; i < 16; ++i) { ad[i] = FLT_MAX; ai[i] = -1; }
    int rc = 0;
    const int ibase = ck * CHUNK;

    auto insert16 = [&](float d, int idx) {
        bool hi = true;
        #pragma unroll
        for (int sl = 15; sl >= 1; --sl) {
            bool sw = d < ad[sl-1];
            float nd = sw ? ad[sl-1] : (hi ? d   : ad[sl]);
            int   ni = sw ? ai[sl-1] : (hi ? idx : ai[sl]);
            ad[sl] = nd; ai[sl] = ni;
            hi = hi && sw;
        }
        ad[0] = hi ? d   : ad[0];
        ai[0] = hi ? idx : ai[0];
    };
    auto drain = [&]() {
        for (int w = 0; w < rc; ++w) {
            float2 e = ring[t * RINGN + w];
            if (e.x < ad[15]) insert16(e.x, __builtin_bit_cast(int, e.y));
        }
        rc = 0;
    };
    auto dist = [&](float4 c) {
        return fmaf(qx2, c.x, fmaf(qy2, c.y, fmaf(qz2, c.z, c.w)));
    };

    // seed: first 16 candidates, unconditional sorted insert
    #pragma unroll
    for (int m = 0; m < 16; ++m) insert16(dist(cl[m]), ibase + m);

    // software-pipelined stream, groups of 8
    float4 cur[8], nxt[8];
    #pragma unroll
    for (int u = 0; u < 8; ++u) cur[u] = cl[16 + u];
    for (int m = 16; m < CHUNK; m += 8) {
        if (m + 8 < CHUNK) {
            #pragma unroll
            for (int u = 0; u < 8; ++u) nxt[u] = cl[m + 8 + u];
        }
        float dv[8];
        #pragma unroll
        for (int u = 0; u < 8; ++u) dv[u] = dist(cur[u]);
        float thr = ad[15];
        #pragma unroll
        for (int u = 0; u < 8; ++u) {
            if (dv[u] < thr) {
                float2 e; e.x = dv[u];
                e.y = __builtin_bit_cast(float, ibase + m + u);
                ring[t * RINGN + rc] = e;
                ++rc;
            }
        }
        if (__any(rc >= DRTH)) drain();
        #pragma unroll
        for (int u = 0; u < 8; ++u) cur[u] = nxt[u];
    }
    drain();

    // write exact chunk top-16
    #pragma unroll
    for (int i = 0; i < 16; ++i) {
        part_d[(q * 4 + ck) * 16 + i] = ad[i];
        part_i[(q * 4 + ck) * 16 + i] = ai[i];
    }
}

// ---------------------------------------------------------------------------
// Kernel 2c: merge 4 partial top-16 -> final top-16 (rank select, idx ties)
// ---------------------------------------------------------------------------
__global__ __launch_bounds__(256, 4)
void knn_merge_kernel(const float* __restrict__ part_d,
                      const int* __restrict__ part_i, int* __restrict__ knn)
{
    __shared__ float sd[4][64];
    __shared__ int   si[4][64];
    const int t = threadIdx.x;
    const int ql = t >> 6, e = t & 63;
    const long q = (long)blockIdx.x * 4 + ql;
    float d = part_d[q * 64 + e];
    int idx = part_i[q * 64 + e];
    sd[ql][e] = d; si[ql][e] = idx;
    __syncthreads();
    int rank = 0;
    #pragma unroll 8
    for (int j = 0; j < 64; ++j) {
        float dj = sd[ql][j];
        rank += ((dj < d) || (dj == d && si[ql][j] < idx)) ? 1 : 0;
    }
    if (rank < 16) knn[q * 16 + rank] = idx;
}

// ---------------------------------------------------------------------------
// Kernel 3: fused attention, MFMA 16x16x32 bf16.  (unchanged from R3)
// ---------------------------------------------------------------------------
#define HS 136   // vpb row stride (bf16)

__device__ inline int hswz(int r, int c) {           // hbuf swizzled index
    return r * 128 + (c ^ ((r & 7) << 4));
}

__global__ __launch_bounds__(256, 2)
void attn_kernel(const float* __restrict__ xyz, const float* __restrict__ feat,
                 const float* __restrict__ d1_w, const float* __restrict__ d1_b,
                 const float* __restrict__ d2_b, const float* __restrict__ g1_b,
                 const float* __restrict__ g2_b,
                 const float* __restrict__ fc2_w, const float* __restrict__ fc2_b,
                 const unsigned short* __restrict__ qb,
                 const unsigned short* __restrict__ kb,
                 const unsigned short* __restrict__ vb,
                 const unsigned short* __restrict__ wd2,
                 const unsigned short* __restrict__ wg1,
                 const unsigned short* __restrict__ wg2,
                 const int* __restrict__ knn, float* __restrict__ out)
{
    __shared__ unsigned short hbuf[128 * 128];  // h1 -> h -> gh (swizzled)
    __shared__ unsigned short vpb [128 * HS];   // v (pure)
    __shared__ unsigned short qsh [8 * 128];
    __shared__ float relb[128 * 4];
    __shared__ float resl[8 * 128];
    __shared__ int   idxs[128];

    const int t    = threadIdx.x;
    const int wave = t >> 6, lane = t & 63;
    const int quad = lane >> 4, l15 = lane & 15;
    const long pbase = (long)blockIdx.x * 8;
    const int b = (int)(pbase >> 13);
    const long bofs = (long)b * NPTS;

    if (t < 128) idxs[t] = knn[(pbase + (t >> 4)) * 16 + (t & 15)];
    __syncthreads();

    {   // qsh staging
        const short4v* src = (const short4v*)(qb + pbase * 128);
        short4v* dst = (short4v*)qsh;
        dst[t] = src[t];
    }
    if (t < 128) {
        int r = t;
        int nn = (int)((pbase + (r >> 4)) & 8191);
        int m = idxs[r];
        const float* xg = xyz + (long)b * 3 * NPTS;
        relb[r*4+0] = xg[nn]        - xg[m];
        relb[r*4+1] = xg[NPTS+nn]   - xg[NPTS+m];
        relb[r*4+2] = xg[2*NPTS+nn] - xg[2*NPTS+m];
        relb[r*4+3] = 0.f;
    }
    {   // v gather: 128 rows x 16 chunks of 8 bf16
        for (int l = t; l < 2048; l += 256) {
            int row = l >> 4, c8 = l & 15;
            const short8* src = (const short8*)(vb + (size_t)(bofs + idxs[row]) * 128 + c8 * 8);
            *(short8*)&vpb[row * HS + c8 * 8] = *src;
        }
    }
    // kg gather into registers (scattered, issued early)
    unsigned short kgu[2][4][8];
    #pragma unroll
    for (int mt = 0; mt < 2; ++mt)
        #pragma unroll
        for (int r = 0; r < 4; ++r) {
            int R = (wave*2 + mt)*16 + quad*4 + r;
            const unsigned short* kp = kb + (size_t)(bofs + idxs[R]) * 128 + l15;
            #pragma unroll
            for (int n0 = 0; n0 < 8; ++n0) kgu[mt][r][n0] = kp[n0 * 16];
        }
    __syncthreads();

    // ---- h1 = relu(rel @ d1.T + b) -> hbuf, vectorized b128 writes ----
    {
        int c8 = t & 15, r0 = t >> 4;
        float w0[8], w1[8], w2[8], bb[8];
        #pragma unroll
        for (int k = 0; k < 8; ++k) {
            int c = c8*8 + k;
            w0[k] = d1_w[c*3]; w1[k] = d1_w[c*3+1]; w2[k] = d1_w[c*3+2];
            bb[k] = d1_b[c];
        }
        #pragma unroll
        for (int i = 0; i < 8; ++i) {
            int row = r0 + 16*i;
            float4 rl = *(const float4*)&relb[row*4];
            short8 hv;
            #pragma unroll
            for (int k = 0; k < 8; ++k) {
                float v = fmaf(w0[k], rl.x, fmaf(w1[k], rl.y, fmaf(w2[k], rl.z, bb[k])));
                hv[k] = (short)f2bf(fmaxf(v, 0.f));
            }
            *(short8*)&hbuf[hswz(row, c8*8)] = hv;
        }
    }
    __syncthreads();

    const int wrow0 = wave * 32;
    short8 A[2][4];
    f32x4 acc[2];

    auto loadA = [&]() {
        #pragma unroll
        for (int mt = 0; mt < 2; ++mt)
            #pragma unroll
            for (int kk = 0; kk < 4; ++kk)
                A[mt][kk] = *(const short8*)&hbuf[hswz(wrow0 + mt*16 + l15, kk*32 + quad*8)];
    };

    unsigned posp[2][8][2];   // packed bf16 pos fragments

    // ============ GEMM 1: pos = h1 @ d2.T + b; h = q - kg + pos ============
    loadA();
    #pragma unroll
    for (int n0 = 0; n0 < 8; ++n0) {
        const unsigned short* wp = wd2 + (n0*16 + l15) * 128 + quad*8;
        short8 B0 = *(const short8*)(wp);
        short8 B1 = *(const short8*)(wp + 32);
        short8 B2 = *(const short8*)(wp + 64);
        short8 B3 = *(const short8*)(wp + 96);
        acc[0] = (f32x4){0.f,0.f,0.f,0.f};
        acc[1] = (f32x4){0.f,0.f,0.f,0.f};
        #pragma unroll
        for (int mt = 0; mt < 2; ++mt) {
            acc[mt] = __builtin_amdgcn_mfma_f32_16x16x32_bf16(A[mt][0], B0, acc[mt], 0, 0, 0);
            acc[mt] = __builtin_amdgcn_mfma_f32_16x16x32_bf16(A[mt][1], B1, acc[mt], 0, 0, 0);
            acc[mt] = __builtin_amdgcn_mfma_f32_16x16x32_bf16(A[mt][2], B2, acc[mt], 0, 0, 0);
            acc[mt] = __builtin_amdgcn_mfma_f32_16x16x32_bf16(A[mt][3], B3, acc[mt], 0, 0, 0);
        }
        int c = n0*16 + l15;
        float bb = d2_b[c];
        #pragma unroll
        for (int mt = 0; mt < 2; ++mt) {
            float qv = bf2f(qsh[(wave*2 + mt)*128 + c]);
            float p0 = acc[mt][0] + bb, p1 = acc[mt][1] + bb;
            float p2 = acc[mt][2] + bb, p3 = acc[mt][3] + bb;
            posp[mt][n0][0] = (unsigned)f2bf(p0) | ((unsigned)f2bf(p1) << 16);
            posp[mt][n0][1] = (unsigned)f2bf(p2) | ((unsigned)f2bf(p3) << 16);
            int rb = wrow0 + mt*16 + quad*4;
            hbuf[hswz(rb+0, c)] = f2bf(qv - bf2f(kgu[mt][0][n0]) + p0);
            hbuf[hswz(rb+1, c)] = f2bf(qv - bf2f(kgu[mt][1][n0]) + p1);
            hbuf[hswz(rb+2, c)] = f2bf(qv - bf2f(kgu[mt][2][n0]) + p2);
            hbuf[hswz(rb+3, c)] = f2bf(qv - bf2f(kgu[mt][3][n0]) + p3);
        }
    }

    // ============ GEMM 2: gh = relu(h @ g1.T + b) ============
    loadA();
    #pragma unroll
    for (int n0 = 0; n0 < 8; ++n0) {
        const unsigned short* wp = wg1 + (n0*16 + l15) * 128 + quad*8;
        short8 B0 = *(const short8*)(wp);
        short8 B1 = *(const short8*)(wp + 32);
        short8 B2 = *(const short8*)(wp + 64);
        short8 B3 = *(const short8*)(wp + 96);
        acc[0] = (f32x4){0.f,0.f,0.f,0.f};
        acc[1] = (f32x4){0.f,0.f,0.f,0.f};
        #pragma unroll
        for (int mt = 0; mt < 2; ++mt) {
            acc[mt] = __builtin_amdgcn_mfma_f32_16x16x32_bf16(A[mt][0], B0, acc[mt], 0, 0, 0);
            acc[mt] = __builtin_amdgcn_mfma_f32_16x16x32_bf16(A[mt][1], B1, acc[mt], 0, 0, 0);
            acc[mt] = __builtin_amdgcn_mfma_f32_16x16x32_bf16(A[mt][2], B2, acc[mt], 0, 0, 0);
            acc[mt] = __builtin_amdgcn_mfma_f32_16x16x32_bf16(A[mt][3], B3, acc[mt], 0, 0, 0);
        }
        int c = n0*16 + l15;
        float bb = g1_b[c];
        #pragma unroll
        for (int mt = 0; mt < 2; ++mt) {
            int rb = wrow0 + mt*16 + quad*4;
            #pragma unroll
            for (int r = 0; r < 4; ++r)
                hbuf[hswz(rb+r, c)] = f2bf(fmaxf(acc[mt][r] + bb, 0.f));
        }
    }

    // ==== GEMM 3: logits -> softmax over K -> res = sum attn*(v+pos) ====
    loadA();
    const float sc = 0.08838834764831845f;
    #pragma unroll
    for (int n0 = 0; n0 < 8; ++n0) {
        const unsigned short* wp = wg2 + (n0*16 + l15) * 128 + quad*8;
        short8 B0 = *(const short8*)(wp);
        short8 B1 = *(const short8*)(wp + 32);
        short8 B2 = *(const short8*)(wp + 64);
        short8 B3 = *(const short8*)(wp + 96);
        acc[0] = (f32x4){0.f,0.f,0.f,0.f};
        acc[1] = (f32x4){0.f,0.f,0.f,0.f};
        #pragma unroll
        for (int mt = 0; mt < 2; ++mt) {
            acc[mt] = __builtin_amdgcn_mfma_f32_16x16x32_bf16(A[mt][0], B0, acc[mt], 0, 0, 0);
            acc[mt] = __builtin_amdgcn_mfma_f32_16x16x32_bf16(A[mt][1], B1, acc[mt], 0, 0, 0);
            acc[mt] = __builtin_amdgcn_mfma_f32_16x16x32_bf16(A[mt][2], B2, acc[mt], 0, 0, 0);
            acc[mt] = __builtin_amdgcn_mfma_f32_16x16x32_bf16(A[mt][3], B3, acc[mt], 0, 0, 0);
        }
        int c = n0*16 + l15;
        float bb = g2_b[c];
        #pragma unroll
        for (int mt = 0; mt < 2; ++mt) {
            float e0 = (acc[mt][0] + bb) * sc;
            float e1 = (acc[mt][1] + bb) * sc;
            float e2 = (acc[mt][2] + bb) * sc;
            float e3 = (acc[mt][3] + bb) * sc;
            float mx = fmaxf(fmaxf(e0, e1), fmaxf(e2, e3));
            mx = fmaxf(mx, __shfl_xor(mx, 16));
            mx = fmaxf(mx, __shfl_xor(mx, 32));
            e0 = __expf(e0 - mx); e1 = __expf(e1 - mx);
            e2 = __expf(e2 - mx); e3 = __expf(e3 - mx);
            float ssum = e0 + e1 + e2 + e3;
            ssum += __shfl_xor(ssum, 16);
            ssum += __shfl_xor(ssum, 32);
            float p0 = bf2f((unsigned short)(posp[mt][n0][0] & 0xffff));
            float p1 = bf2f((unsigned short)(posp[mt][n0][0] >> 16));
            float p2 = bf2f((unsigned short)(posp[mt][n0][1] & 0xffff));
            float p3 = bf2f((unsigned short)(posp[mt][n0][1] >> 16));
            int rowb = (wrow0 + mt*16 + quad*4) * HS + c;
            float p = e0 * (bf2f(vpb[rowb])        + p0)
                    + e1 * (bf2f(vpb[rowb + HS])   + p1)
                    + e2 * (bf2f(vpb[rowb + 2*HS]) + p2)
                    + e3 * (bf2f(vpb[rowb + 3*HS]) + p3);
            p += __shfl_xor(p, 16);
            p += __shfl_xor(p, 32);
            if (quad == 0) resl[(wave*2 + mt)*128 + c] = p / ssum;
        }
    }
    __syncthreads();

    // ---- epilogue: out = res @ fc2.T + b + feat ----
    {
        int pt = t >> 5, j = t & 31;
        #pragma unroll
        for (int dp = 0; dp < 3; ++dp) {
            float part = 0.f;
            #pragma unroll
            for (int i = 0; i < 4; ++i) {
                int cc = j + 32*i;
                part = fmaf(fc2_w[dp*128 + cc], resl[pt*128 + cc], part);
            }
            part += __shfl_down(part, 16, 32);
            part += __shfl_down(part, 8, 32);
            part += __shfl_down(part, 4, 32);
            part += __shfl_down(part, 2, 32);
            part += __shfl_down(part, 1, 32);
            if (j == 0) {
                int nn = (int)((pbase + pt) & 8191);
                long o = ((long)b*3 + dp) * NPTS + nn;
                out[o] = part + fc2_b[dp] + feat[o];
            }
        }
    }
}

// ---------------------------------------------------------------------------
extern "C" void kernel_launch(void* const* d_in, const int* in_sizes, int n_in,
                              void* d_out, int out_size, void* d_ws, size_t ws_size,
                              hipStream_t stream)
{
    const float* xyz   = (const float*)d_in[0];
    const float* feat  = (const float*)d_in[1];
    const float* fc1_w = (const float*)d_in[2];
    const float* fc1_b = (const float*)d_in[3];
    const float* fc2_w = (const float*)d_in[4];
    const float* fc2_b = (const float*)d_in[5];
    const float* d1_w  = (const float*)d_in[6];
    const float* d1_b  = (const float*)d_in[7];
    const float* d2_w  = (const float*)d_in[8];
    const float* d2_b  = (const float*)d_in[9];
    const float* g1_w  = (const float*)d_in[10];
    const float* g1_b  = (const float*)d_in[11];
    const float* g2_w  = (const float*)d_in[12];
    const float* g2_b  = (const float*)d_in[13];
    const float* wq_w  = (const float*)d_in[14];
    const float* wk_w  = (const float*)d_in[15];
    const float* wv_w  = (const float*)d_in[16];
    float* out = (float*)d_out;

    unsigned short* qb  = (unsigned short*)d_ws;      // 16384*128 bf16
    unsigned short* kb  = qb + (size_t)16384*128;
    unsigned short* vb  = kb + (size_t)16384*128;
    unsigned short* wd2 = vb + (size_t)16384*128;     // 128*128 bf16 each
    unsigned short* wg1 = wd2 + 16384;
    unsigned short* wg2 = wg1 + 16384;
    int*   knn_ws = (int*)(wg2 + 16384);              // 16384*16 i32
    float4* cand  = (float4*)(knn_ws + (size_t)16384*16);   // 16384 float4
    float* part_d = (float*)(cand + 16384);           // 16384*64 f32
    int*   part_i = (int*)(part_d + (size_t)16384*64);// 16384*64 i32

    hipLaunchKernelGGL(wconv_kernel, dim3(192), dim3(256), 0, stream,
                       d2_w, g1_w, g2_w, wd2, wg1, wg2);
    hipLaunchKernelGGL(candprep_kernel, dim3(64), dim3(256), 0, stream, xyz, cand);
    hipLaunchKernelGGL(knn_part_kernel, dim3(256), dim3(256), 0, stream,
                       cand, part_d, part_i);
    hipLaunchKernelGGL(knn_merge_kernel, dim3(4096), dim3(256), 0, stream,
                       part_d, part_i, knn_ws);
    hipLaunchKernelGGL(proj_kernel, dim3(2048), dim3(128), 0, stream,
                       feat, fc1_w, fc1_b, wq_w, wk_w, wv_w, qb, kb, vb);
    hipLaunchKernelGGL(attn_kernel, dim3(2048), dim3(256), 0, stream,
                       xyz, feat, d1_w, d1_b, d2_b, g1_b, g2_b, fc2_w, fc2_b,
                       qb, kb, vb, wd2, wg1, wg2, knn_ws, out);
}